// Round 10
// baseline (111.416 us; speedup 1.0000x reference)
//
#include <hip/hip_runtime.h>
#include <stdint.h>

constexpr int K      = 49;           // 7x7 kernel flattened
constexpr int C      = 32;           // out channels
constexpr int TILE   = 64;           // windows per tile
constexpr int TILE_F = TILE * K;     // 3136 floats = 12544 B
constexpr int BLK    = 256;          // 4 waves/block
constexpr int NT     = 8;            // tiles per block
constexpr int GRID   = 2048;         // 2048*8*64 = 1048576 windows
constexpr int CPW    = C / 4;        // 8 channels per wave

#define GPTR(p) ((const __attribute__((address_space(1))) uint32_t*)(p))
#define LPTR(p) ((__attribute__((address_space(3))) uint32_t*)(p))
#define WAITV(n) asm volatile("s_waitcnt vmcnt(" #n ")" ::: "memory")

// Wave's share of one 12544B tile stage: waves 0-2 -> 3 x (64 lane x 16B),
// wave 3 -> 3 x 16B rounds + 64-lane 4B tail. Lw = 3,3,3,4 VMEM ops.
// LDS dest = uniform base + lane*width (global_load_lds HW requirement).
__device__ __forceinline__ void stage_share(const float* __restrict__ g,
                                            float* slot, int wid, int lane) {
    if (wid < 3) {
#pragma unroll
        for (int r = 0; r < 3; ++r) {
            const int rr = wid * 3 + r;
            __builtin_amdgcn_global_load_lds(GPTR(g + rr * 256 + lane * 4),
                                             LPTR(slot + rr * 256 + lane * 4), 16, 0, 0);
        }
    } else {
#pragma unroll
        for (int rr = 9; rr < 12; ++rr)
            __builtin_amdgcn_global_load_lds(GPTR(g + rr * 256 + lane * 4),
                                             LPTR(slot + rr * 256 + lane * 4), 16, 0, 0);
        __builtin_amdgcn_global_load_lds(GPTR(g + 3072 + lane),
                                         LPTR(slot + 3072 + lane), 4, 0, 0);
    }
}

// Ring-2 pipelined tile stream. Per-wave VMEM FIFO per iter j:
//   issue: ... P_j | S_{j-1}(8) | [wait here] P_{j+1}(Lw) ...
// In-order vmcnt retirement: "outstanding <= 8" <=> P_j retired; the 8
// younger stores never chain the wait. No vmcnt(0) anywhere in the loop.
__global__ __launch_bounds__(BLK, 6) void conv2d_pipe(
    const float* __restrict__ enc_x,
    const float* __restrict__ weight,   // [C*K]; uniform base -> s_load_dwordx16
    const float* __restrict__ bias,     // [C]
    float* __restrict__ out,            // [C * windows_nb]
    int windows_nb)
{
    __shared__ __align__(16) float buf0[TILE_F];   // 12544 B
    __shared__ __align__(16) float buf1[TILE_F];   // -> 25088 B, 6 blocks/CU

    const int t    = threadIdx.x;
    const int lane = t & 63;
    const int widv = t >> 6;                       // divergent form: staging only
    const size_t b = blockIdx.x;
    const float* __restrict__ gbase = enc_x + b * (size_t)(NT * TILE_F);

    // Prologue: stage tile 0.
    stage_share(gbase, buf0, widv, lane);

    // Wave-uniform channel base (SGPR) -> weight/bias/out reads stay SCALAR.
    const int c0 = __builtin_amdgcn_readfirstlane(widv) * CPW;
    const float* __restrict__ wp = weight + c0 * K;
    float bia[CPW];
#pragma unroll
    for (int cc = 0; cc < CPW; ++cc) bia[cc] = bias[c0 + cc];

#pragma unroll
    for (int j = 0; j < NT; ++j) {
        if (j == 0) WAITV(0);          // only own P0 outstanding
        else        WAITV(8);          // own S_{j-1} may stay in flight
        __builtin_amdgcn_s_barrier();  // whole tile j resident (all waves waited)

        float* __restrict__ cur = (j & 1) ? buf1 : buf0;
        float* __restrict__ nxt = (j & 1) ? buf0 : buf1;

        // Prefetch tile j+1 into tile j-1's buffer: every wave past barrier_j
        // consumed its tile j-1 ds_reads (fed iter j-1's FMAs) -> safe.
        if (j + 1 < NT)
            stage_share(gbase + (size_t)(j + 1) * TILE_F, nxt, widv, lane);

        // Lane's window row -> regs. Stride 49 (odd) -> 2 lanes/bank -> free.
        float x[K];
#pragma unroll
        for (int k = 0; k < K; ++k) x[k] = cur[lane * K + k];

        const size_t w = (b * NT + j) * (size_t)TILE + lane;

        // 8 channels, c-outer, k fully unrolled: 49 consecutive weights ->
        // wide s_loads; unroll 2 pipelines next channel's s_loads under FMAs.
#pragma unroll 2
        for (int cc = 0; cc < CPW; ++cc) {
            const float* __restrict__ wc = wp + cc * K;
            float a0 = bia[cc], a1 = 0.f, a2 = 0.f, a3 = 0.f;
#pragma unroll
            for (int k = 0; k < K; k += 4) {
                a0 = fmaf(x[k], wc[k], a0);
                if (k + 1 < K) a1 = fmaf(x[k + 1], wc[k + 1], a1);
                if (k + 2 < K) a2 = fmaf(x[k + 2], wc[k + 2], a2);
                if (k + 3 < K) a3 = fmaf(x[k + 3], wc[k + 3], a3);
            }
            // nt store: don't evict enc_x from L2/L3 with streaming output
            __builtin_nontemporal_store((a0 + a1) + (a2 + a3),
                                        &out[(size_t)(c0 + cc) * windows_nb + w]);
        }
    }
}

// Known-good fallback (R9, 79.5us) for unexpected sizes.
__global__ __launch_bounds__(128, 8) void conv2d_split2u(
    const float* __restrict__ enc_x, const float* __restrict__ weight,
    const float* __restrict__ bias, float* __restrict__ out, int windows_nb)
{
    __shared__ __align__(16) float xs[TILE_F];
    const int t = threadIdx.x, lane = t & 63, wid = t >> 6;
    const size_t b = blockIdx.x;
    const float* __restrict__ g = enc_x + b * (size_t)TILE_F;
    if (wid == 0) {
#pragma unroll
        for (int r = 0; r < 6; ++r)
            __builtin_amdgcn_global_load_lds(GPTR(g + r * 256 + lane * 4),
                                             LPTR(xs + r * 256 + lane * 4), 16, 0, 0);
    } else {
#pragma unroll
        for (int r = 6; r < 12; ++r)
            __builtin_amdgcn_global_load_lds(GPTR(g + r * 256 + lane * 4),
                                             LPTR(xs + r * 256 + lane * 4), 16, 0, 0);
        __builtin_amdgcn_global_load_lds(GPTR(g + 3072 + lane),
                                         LPTR(xs + 3072 + lane), 4, 0, 0);
    }
    asm volatile("s_waitcnt vmcnt(0)" ::: "memory");
    __builtin_amdgcn_s_barrier();
    const int c0 = __builtin_amdgcn_readfirstlane(wid) * 16;
    const float* __restrict__ wp = weight + c0 * K;
    float acc[16];
#pragma unroll
    for (int cc = 0; cc < 16; ++cc) acc[cc] = bias[c0 + cc];
    float x[25];
#pragma unroll
    for (int k = 0; k < 24; ++k) x[k] = xs[lane * K + k];
#pragma unroll 2
    for (int cc = 0; cc < 16; ++cc) {
        const float* __restrict__ wc = wp + cc * K;
        float a = acc[cc];
#pragma unroll
        for (int k = 0; k < 24; ++k) a = fmaf(x[k], wc[k], a);
        acc[cc] = a;
    }
#pragma unroll
    for (int k = 0; k < 25; ++k) x[k] = xs[lane * K + 24 + k];
#pragma unroll 2
    for (int cc = 0; cc < 16; ++cc) {
        const float* __restrict__ wc = wp + cc * K + 24;
        float a = acc[cc];
#pragma unroll
        for (int k = 0; k < 25; ++k) a = fmaf(x[k], wc[k], a);
        acc[cc] = a;
    }
    const size_t w = b * TILE + lane;
#pragma unroll
    for (int cc = 0; cc < 16; ++cc)
        out[(size_t)(c0 + cc) * windows_nb + w] = acc[cc];
}

extern "C" void kernel_launch(void* const* d_in, const int* in_sizes, int n_in,
                              void* d_out, int out_size, void* d_ws, size_t ws_size,
                              hipStream_t stream) {
    const float* enc_x  = (const float*)d_in[0];
    const float* weight = (const float*)d_in[1];   // [C,7,7] flat
    const float* bias   = (const float*)d_in[2];   // [C]
    float* out = (float*)d_out;

    const int windows_nb = in_sizes[0] / K;        // 1048576 expected

    if (windows_nb == GRID * NT * TILE) {
        conv2d_pipe<<<GRID, BLK, 0, stream>>>(enc_x, weight, bias, out, windows_nb);
    } else {
        conv2d_split2u<<<windows_nb / TILE, 128, 0, stream>>>(enc_x, weight, bias, out, windows_nb);
    }
}